// Round 6
// baseline (5462.111 us; speedup 1.0000x reference)
//
#include <hip/hip_runtime.h>
#include <stdint.h>

#define T_STEPS 512

typedef short short8 __attribute__((ext_vector_type(8)));
typedef float floatx4 __attribute__((ext_vector_type(4)));

#define MFMA16 __builtin_amdgcn_mfma_f32_16x16x32_bf16

__device__ __forceinline__ unsigned short f2bf(float f) {
  unsigned int u = __builtin_bit_cast(unsigned int, f);
  u = u + 0x7fff + ((u >> 16) & 1);
  return (unsigned short)(u >> 16);
}
__device__ __forceinline__ float bf2f(unsigned short s) {
  unsigned int u = ((unsigned int)s) << 16;
  return __builtin_bit_cast(float, u);
}
__device__ __forceinline__ float sigm(float x) { return 1.f / (1.f + __expf(-x)); }
__device__ __forceinline__ float tanh_fast(float x) {
  float e2 = __expf(2.f * x);
  return 1.f - 2.f / (e2 + 1.f);
}

__device__ __forceinline__ void gload16(const void* g, const void* l) {
  __builtin_amdgcn_global_load_lds((const __attribute__((address_space(1))) unsigned int*)g,
                                   (__attribute__((address_space(3))) unsigned int*)l,
                                   16, 0, 0);
}

// LLC-coherent (cross-XCD) data exchange: bypass L1+L2 both ways.
__device__ __forceinline__ short8 ld16x(const unsigned short* p) {
  short8 r;
  asm volatile("global_load_dwordx4 %0, %1, off sc0 sc1" : "=v"(r) : "v"(p));
  return r;
}
__device__ __forceinline__ void st2x(unsigned short* p, unsigned short v) {
  unsigned int vv = v;
  asm volatile("global_store_short %0, %1, off sc0 sc1" :: "v"(p), "v"(vv));
}
__device__ __forceinline__ void drain_vm() {
  asm volatile("s_waitcnt vmcnt(0)" ::: "memory");
}
// Lane-parallel flag poll: lane i watches flag i. Bounded spin (no hang).
__device__ __forceinline__ void poll_flags(unsigned int* f, unsigned int target) {
  unsigned int* p = f + (threadIdx.x & 63);
  int spins = 0;
  do {
    unsigned int v = __hip_atomic_load(p, __ATOMIC_RELAXED, __HIP_MEMORY_SCOPE_AGENT);
    if (__all((int)(v >= target))) break;
    if (spins > 8) __builtin_amdgcn_s_sleep(1);
  } while (++spins < (1 << 16));
  __builtin_amdgcn_sched_barrier(0);
}

// ---------------------------------------------------------------------------
__global__ void pack_bf(const float* __restrict__ in, unsigned short* __restrict__ out, int n) {
  int i = blockIdx.x * 256 + threadIdx.x;
  if (i < n) out[i] = f2bf(in[i]);
}

__global__ void packT(const float* __restrict__ src, int srcStride,
                      unsigned short* __restrict__ dst, int dldk, int koff) {
  __shared__ float tile[32][33];
  int tx = threadIdx.x, ty = threadIdx.y;
  int e0 = blockIdx.x * 32, k0 = blockIdx.y * 32;
#pragma unroll
  for (int i = 0; i < 4; ++i)
    tile[ty + 8 * i][tx] = src[(size_t)(k0 + ty + 8 * i) * srcStride + e0 + tx];
  __syncthreads();
#pragma unroll
  for (int i = 0; i < 4; ++i)
    dst[(size_t)(e0 + ty + 8 * i) * dldk + koff + k0 + tx] = f2bf(tile[tx][ty + 8 * i]);
}

__global__ void sentinel(float* out, float v) { out[0] = v; }

// ---------------------------------------------------------------------------
// Big MFMA GEMM (unchanged, verified)
// ---------------------------------------------------------------------------
template <int EPI>
__global__ __launch_bounds__(256) void gemm_bt(
    const unsigned short* __restrict__ A0, const unsigned short* __restrict__ A1,
    const unsigned short* __restrict__ BT,
    int M, int Nn, int K, int KA0,
    const float* __restrict__ bias,
    unsigned short* __restrict__ out_bf,
    const float* __restrict__ xf,
    float* __restrict__ ud,
    unsigned short* __restrict__ rdx,
    float* __restrict__ outf) {
  __shared__ unsigned short At[128 * 32];
  __shared__ unsigned short Bt[128 * 32];
  const int tid = threadIdx.x;
  const int lane = tid & 63, wave = tid >> 6;
  const int wm = wave >> 1, wn = wave & 1;
  const int m0 = blockIdx.y * 128, n0 = blockIdx.x * 128;
  const int lr = lane & 15, lk = (lane >> 4) * 8;
  floatx4 acc[4][4] = {};

  for (int k0 = 0; k0 < K; k0 += 32) {
    const unsigned short* As;
    int kk;
    if (k0 < KA0) { As = A0 + (size_t)m0 * KA0 + k0; kk = KA0; }
    else          { As = A1 + (size_t)m0 * (K - KA0) + (k0 - KA0); kk = K - KA0; }
#pragma unroll
    for (int j = 0; j < 2; ++j) {
      int chunk = j * 256 + tid;
      int row = chunk >> 2, kc = chunk & 3;
      gload16(As + (size_t)row * kk + kc * 8, (const char*)At + chunk * 16);
    }
    const unsigned short* Bs = BT + (size_t)n0 * K + k0;
#pragma unroll
    for (int j = 0; j < 2; ++j) {
      int chunk = j * 256 + tid;
      int row = chunk >> 2, kc = chunk & 3;
      gload16(Bs + (size_t)row * K + kc * 8, (const char*)Bt + chunk * 16);
    }
    __syncthreads();
    short8 a[4], b[4];
#pragma unroll
    for (int i = 0; i < 4; ++i) a[i] = *(const short8*)(At + (wm * 64 + i * 16 + lr) * 32 + lk);
#pragma unroll
    for (int i = 0; i < 4; ++i) b[i] = *(const short8*)(Bt + (wn * 64 + i * 16 + lr) * 32 + lk);
#pragma unroll
    for (int i = 0; i < 4; ++i)
#pragma unroll
      for (int j = 0; j < 4; ++j)
        acc[i][j] = MFMA16(a[i], b[j], acc[i][j], 0, 0, 0);
    __syncthreads();
  }

#pragma unroll
  for (int i = 0; i < 4; ++i) {
#pragma unroll
    for (int j = 0; j < 4; ++j) {
      int col = n0 + wn * 64 + j * 16 + lr;
#pragma unroll
      for (int r = 0; r < 4; ++r) {
        int row = m0 + wm * 64 + i * 16 + (lane >> 4) * 4 + r;
        float v = acc[i][j][r];
        if constexpr (EPI == 0) {
          out_bf[(size_t)row * Nn + col] = f2bf(v + bias[col]);
        } else if constexpr (EPI == 1) {
          float s = sigm(v + bias[col]);
          if (col < 1024) {
            ud[(size_t)row * 1024 + col] = s;
          } else {
            size_t ix = (size_t)row * 1024 + (col - 1024);
            rdx[ix] = f2bf(s * xf[ix]);
          }
        } else {
          float hc = tanh_fast(v + bias[col]);
          size_t ix = (size_t)row * 1024 + col;
          float xv = xf[ix];
          outf[ix] = xv + ud[ix] * (hc - xv);
        }
      }
    }
  }
}

// ---------------------------------------------------------------------------
// Persistent scan (r6). 128 blocks = 2 groups x 64 (PROVEN co-resident at r3/r4).
// Group g: batch rows [g*16,g*16+16). Block b: cols [b*16,b*16+16). Each thread
// owns one (row,col) element -> Hl, u are scalar regs. Weights (Wu,Wr,Wc slices,
// 96KB) LDS-resident, XOR-swizzled. Cross-block data via sc0sc1 (LLC) loads/
// stores; flags via relaxed agent atomics; NO acquire-invalidate (L2 stays warm).
// Per step: poll fB -> h frags (K-quarter/wave, global->VGPR) -> r+u MFMA
// (interleaved chains) -> combine -> rh store + fA -> poll fA (u already done)
// -> rh frags -> hc MFMA -> combine -> h update + store + fB.
// ---------------------------------------------------------------------------
__global__ __launch_bounds__(256, 1) void scan_pk(
    const unsigned short* __restrict__ wgT,   // [2048][1024] u-cols 0-1023, r-cols 1024-2047
    const unsigned short* __restrict__ wcT,   // [1024][1024]
    const unsigned short* __restrict__ gates, // [32*512][3072]
    const float* __restrict__ ph,             // [32][1024]
    unsigned short* __restrict__ hb,          // [32][1024] broadcast h (bf16)
    unsigned short* __restrict__ rhbuf,       // [32][1024] broadcast r*h (bf16)
    unsigned short* __restrict__ htb,         // [32*512][1024]
    float* __restrict__ lastht,               // [32][1024]
    unsigned int* __restrict__ ctl)           // [2 groups][fA 64 | fB 64]
{
  __shared__ unsigned short Wu[16 * 1024];
  __shared__ unsigned short Wr[16 * 1024];
  __shared__ unsigned short Wc[16 * 1024];
  __shared__ float Part[8][16][17];           // [0..3]=r / hc, [4..7]=u

  const int tid = threadIdx.x;
  const int lane = tid & 63, wave = tid >> 6;
  const int lr = lane & 15, lq = lane >> 4;
  const int g = blockIdx.x >> 6, b = blockIdx.x & 63;
  const int row0 = g * 16, col0 = b * 16;
  const int myrow = tid >> 4, myc = tid & 15;
  unsigned int* fA = ctl + g * 128;
  unsigned int* fB = fA + 64;

  // ---- stage weight slices into LDS (source pre-swizzled: chunk ^= col&7) ----
#pragma unroll
  for (int i = 0; i < 8; ++i) {
    int p = i * 256 + tid;                 // 2048 chunks of 16B per array
    int wr = p >> 7, kcp = p & 127;
    int kc = kcp ^ (wr & 7);
    gload16(wgT + (size_t)(col0 + wr) * 1024 + kc * 8,          (const char*)Wu + p * 16);
    gload16(wgT + (size_t)(1024 + col0 + wr) * 1024 + kc * 8,   (const char*)Wr + p * 16);
    gload16(wcT + (size_t)(col0 + wr) * 1024 + kc * 8,          (const char*)Wc + p * 16);
  }

  // ---- init: per-thread h element ----
  float Hl = ph[(size_t)(row0 + myrow) * 1024 + col0 + myc];
  st2x(&hb[(size_t)(row0 + myrow) * 1024 + col0 + myc], f2bf(Hl));
  drain_vm();
  __syncthreads();                         // weights resident + hb stores drained
  if (tid == 0)
    __hip_atomic_store(&fB[b], 1u, __ATOMIC_RELAXED, __HIP_MEMORY_SCOPE_AGENT);

  for (int t = 0; t < T_STEPS; ++t) {
    // gate prefetch (plain cached; L2 stays warm — no invalidates in this design)
    size_t gbase = ((size_t)(row0 + myrow) * T_STEPS + t) * 3072 + col0 + myc;
    unsigned short gU = gates[gbase];
    unsigned short gR = gates[gbase + 1024];
    unsigned short gC = gates[gbase + 2048];

    poll_flags(fB, (unsigned)(t + 1));     // h(t) visible at LLC

    // ---- h fragments: wave w loads its K-quarter, global->VGPR ----
    short8 av[8];
    {
      const unsigned short* hsrc = hb + (size_t)(row0 + lr) * 1024 + wave * 256 + lq * 8;
#pragma unroll
      for (int kc = 0; kc < 8; ++kc) av[kc] = ld16x(hsrc + kc * 32);
    }
    drain_vm();
    __builtin_amdgcn_sched_barrier(0);

    // ---- r + u MFMA (two independent chains over shared av) ----
    {
      floatx4 aR = {}, aU = {};
#pragma unroll
      for (int kc = 0; kc < 8; ++kc) {
        int ch = (wave * 32 + kc * 4 + lq) ^ (lr & 7);
        short8 bR = *(const short8*)(Wr + lr * 1024 + ch * 8);
        short8 bU = *(const short8*)(Wu + lr * 1024 + ch * 8);
        aR = MFMA16(av[kc], bR, aR, 0, 0, 0);
        aU = MFMA16(av[kc], bU, aU, 0, 0, 0);
      }
#pragma unroll
      for (int r = 0; r < 4; ++r) {
        Part[wave][lq * 4 + r][lr] = aR[r];
        Part[4 + wave][lq * 4 + r][lr] = aU[r];
      }
    }
    __syncthreads();
    float uv;
    {
      float rpre = Part[0][myrow][myc] + Part[1][myrow][myc] +
                   Part[2][myrow][myc] + Part[3][myrow][myc];
      float upre = Part[4][myrow][myc] + Part[5][myrow][myc] +
                   Part[6][myrow][myc] + Part[7][myrow][myc];
      float rv = sigm(rpre + bf2f(gR));
      uv = sigm(upre + bf2f(gU));
      st2x(&rhbuf[(size_t)(row0 + myrow) * 1024 + col0 + myc], f2bf(rv * Hl));
    }
    drain_vm();
    __syncthreads();                       // all 4 waves' rh stores at LLC
    if (tid == 0)
      __hip_atomic_store(&fA[b], (unsigned)(t + 1), __ATOMIC_RELAXED,
                         __HIP_MEMORY_SCOPE_AGENT);

    poll_flags(fA, (unsigned)(t + 1));     // rh visible

    // ---- rh fragments ----
    short8 av2[8];
    {
      const unsigned short* rsrc = rhbuf + (size_t)(row0 + lr) * 1024 + wave * 256 + lq * 8;
#pragma unroll
      for (int kc = 0; kc < 8; ++kc) av2[kc] = ld16x(rsrc + kc * 32);
    }
    drain_vm();
    __builtin_amdgcn_sched_barrier(0);

    // ---- hc MFMA (two chains) ----
    {
      floatx4 c0 = {}, c1 = {};
#pragma unroll
      for (int kc = 0; kc < 8; kc += 2) {
        int ch0 = (wave * 32 + kc * 4 + lq) ^ (lr & 7);
        int ch1 = (wave * 32 + (kc + 1) * 4 + lq) ^ (lr & 7);
        short8 b0 = *(const short8*)(Wc + lr * 1024 + ch0 * 8);
        short8 b1 = *(const short8*)(Wc + lr * 1024 + ch1 * 8);
        c0 = MFMA16(av2[kc], b0, c0, 0, 0, 0);
        c1 = MFMA16(av2[kc + 1], b1, c1, 0, 0, 0);
      }
#pragma unroll
      for (int r = 0; r < 4; ++r) Part[wave][lq * 4 + r][lr] = c0[r] + c1[r];
    }
    __syncthreads();
    {
      float cpre = Part[0][myrow][myc] + Part[1][myrow][myc] +
                   Part[2][myrow][myc] + Part[3][myrow][myc];
      float hc = tanh_fast(cpre + bf2f(gC));
      float hn = Hl + uv * (hc - Hl);
      Hl = hn;
      unsigned short hv = f2bf(hn);
      st2x(&hb[(size_t)(row0 + myrow) * 1024 + col0 + myc], hv);
      htb[((size_t)(row0 + myrow) * T_STEPS + t) * 1024 + col0 + myc] = hv;
      if (t == T_STEPS - 1) lastht[(size_t)(row0 + myrow) * 1024 + col0 + myc] = hn;
    }
    drain_vm();
    __syncthreads();                       // h(t+1) stores at LLC
    if (tid == 0)
      __hip_atomic_store(&fB[b], (unsigned)(t + 2), __ATOMIC_RELAXED,
                         __HIP_MEMORY_SCOPE_AGENT);
  }
}

// ---------------------------------------------------------------------------
extern "C" void kernel_launch(void* const* d_in, const int* in_sizes, int n_in,
                              void* d_out, int out_size, void* d_ws, size_t ws_size,
                              hipStream_t stream) {
  const float* x    = (const float*)d_in[0];   // (32,512,1024)
  const float* ph   = (const float*)d_in[1];   // (32,1024)
  const float* wgt  = (const float*)d_in[2];   // (2048,6144)
  const float* bias = (const float*)d_in[3];   // (6144,)
  float* out = (float*)d_out;                  // h (16777216) + last_ht (32768)

  const size_t SZ_CTL   = 16384;                      // flags 2*128 u32 used
  const size_t SZ_XBF   = (size_t)16384 * 1024 * 2;
  const size_t SZ_GATES = (size_t)16384 * 3072 * 2;   // rdx aliases here after scan
  const size_t SZ_HTB   = (size_t)16384 * 1024 * 2;
  const size_t SZ_W     = ((size_t)3072 * 1024 + (size_t)2048 * 2048 +
                           (size_t)1024 * 2048 + (size_t)2048 * 1024 +
                           (size_t)1024 * 1024) * 2;
  const size_t SZ_SMALL = (size_t)(32 * 1024) * (2 + 2); // hb, rhbuf
  const size_t REQUIRED = SZ_CTL + SZ_XBF + SZ_GATES + SZ_HTB + SZ_W + SZ_SMALL;

  if (ws_size < REQUIRED) {
    sentinel<<<1, 1, 0, stream>>>(out, (float)ws_size);
    return;
  }

  char* p = (char*)d_ws;
  unsigned int* ctl     = (unsigned int*)p;   p += SZ_CTL;
  unsigned short* xbf   = (unsigned short*)p; p += SZ_XBF;
  unsigned short* gates = (unsigned short*)p;
  unsigned short* rdx   = (unsigned short*)p; p += SZ_GATES;
  unsigned short* htb   = (unsigned short*)p; p += SZ_HTB;
  unsigned short* wxtT  = (unsigned short*)p; p += (size_t)3072 * 1024 * 2;
  unsigned short* w1T   = (unsigned short*)p; p += (size_t)2048 * 2048 * 2;
  unsigned short* w2T   = (unsigned short*)p; p += (size_t)1024 * 2048 * 2;
  unsigned short* wgT   = (unsigned short*)p; p += (size_t)2048 * 1024 * 2;
  unsigned short* wcT   = (unsigned short*)p; p += (size_t)1024 * 1024 * 2;
  unsigned short* hb    = (unsigned short*)p; p += (size_t)32 * 1024 * 2;
  unsigned short* rhbuf = (unsigned short*)p; p += (size_t)32 * 1024 * 2;
  float* udf = out;  // ud aliases d_out's h region; see gemm epilogues

  hipMemsetAsync(ctl, 0, SZ_CTL, stream);     // step-sense flags start at 0

  dim3 tb(32, 8);
  pack_bf<<<65536, 256, 0, stream>>>(x, xbf, 16384 * 1024);
  packT<<<dim3(96, 32), tb, 0, stream>>>(wgt, 6144, wxtT, 1024, 0);
  packT<<<dim3(64, 64), tb, 0, stream>>>(wgt + 3072, 6144, w1T, 2048, 0);
  packT<<<dim3(32, 32), tb, 0, stream>>>(wgt + (size_t)1024 * 6144 + 5120, 6144, w2T, 2048, 0);
  packT<<<dim3(32, 32), tb, 0, stream>>>(wgt + 5120, 6144, w2T, 2048, 1024);
  packT<<<dim3(64, 32), tb, 0, stream>>>(wgt + (size_t)1024 * 6144, 6144, wgT, 1024, 0);
  packT<<<dim3(32, 32), tb, 0, stream>>>(wgt + (size_t)1024 * 6144 + 2048, 6144, wcT, 1024, 0);

  gemm_bt<0><<<dim3(24, 128), 256, 0, stream>>>(xbf, xbf, wxtT, 16384, 3072, 1024, 1024,
                                                bias, gates, nullptr, nullptr, nullptr, nullptr);

  // persistent recurrence: 128 blocks (proven co-resident), 2 groups x 64
  scan_pk<<<128, 256, 0, stream>>>(wgT, wcT, gates, ph, hb, rhbuf, htb,
                                   out + (size_t)16384 * 1024, ctl);

  gemm_bt<1><<<dim3(16, 128), 256, 0, stream>>>(xbf, htb, w1T, 16384, 2048, 2048, 1024,
                                                bias + 3072, nullptr, x, udf, rdx, nullptr);
  gemm_bt<2><<<dim3(8, 128), 256, 0, stream>>>(htb, rdx, w2T, 16384, 1024, 2048, 1024,
                                               bias + 5120, nullptr, x, udf, nullptr, out);
}

// Round 7
// 5039.657 us; speedup vs baseline: 1.0838x; 1.0838x over previous
//
#include <hip/hip_runtime.h>
#include <stdint.h>

#define T_STEPS 512

typedef short short8 __attribute__((ext_vector_type(8)));
typedef float floatx4 __attribute__((ext_vector_type(4)));
typedef unsigned int u32x4 __attribute__((ext_vector_type(4)));

#define MFMA16 __builtin_amdgcn_mfma_f32_16x16x32_bf16

__device__ __forceinline__ unsigned short f2bf(float f) {
  unsigned int u = __builtin_bit_cast(unsigned int, f);
  u = u + 0x7fff + ((u >> 16) & 1);
  return (unsigned short)(u >> 16);
}
__device__ __forceinline__ float bf2f(unsigned short s) {
  unsigned int u = ((unsigned int)s) << 16;
  return __builtin_bit_cast(float, u);
}
__device__ __forceinline__ float sigm(float x) { return 1.f / (1.f + __expf(-x)); }
__device__ __forceinline__ float tanh_fast(float x) {
  float e2 = __expf(2.f * x);
  return 1.f - 2.f / (e2 + 1.f);
}

__device__ __forceinline__ void gload16(const void* g, const void* l) {
  __builtin_amdgcn_global_load_lds((const __attribute__((address_space(1))) unsigned int*)g,
                                   (__attribute__((address_space(3))) unsigned int*)l,
                                   16, 0, 0);
}

// Fire-and-forget tagged-word store (LLC-coherent, no drain needed).
__device__ __forceinline__ void st_tag(unsigned int* p, unsigned int word) {
  asm volatile("global_store_dword %0, %1, off sc0 sc1" :: "v"(p), "v"(word) : "memory");
}

// Poll a wave's 8 MFMA A-fragments (8x 32B of tagged u32 words) until every
// word's tag >= target, then unpack payloads to bf16 frags. One LLC RT per
// retry (all 16 dwordx4 issued before a single vmcnt wait). Bounded spin.
__device__ __forceinline__ void poll_frags(const unsigned int* base, unsigned int target,
                                           short8* av) {
  int spins = 0;
  for (;;) {
    u32x4 w[16];
#pragma unroll
    for (int i = 0; i < 8; ++i) {
      asm volatile("global_load_dwordx4 %0, %1, off sc0 sc1" : "=v"(w[2 * i]) : "v"(base + i * 32));
      asm volatile("global_load_dwordx4 %0, %1, off sc0 sc1" : "=v"(w[2 * i + 1]) : "v"(base + i * 32 + 4));
    }
    asm volatile("s_waitcnt vmcnt(0)" ::: "memory");
    __builtin_amdgcn_sched_barrier(0);
    bool ok = true;
#pragma unroll
    for (int i = 0; i < 16; ++i)
#pragma unroll
      for (int j = 0; j < 4; ++j) ok &= ((w[i][j] >> 16) >= target);
    bool done = __all((int)ok) || (++spins > 4096);   // valve: wrong answer > hang
    if (done) {
#pragma unroll
      for (int i = 0; i < 8; ++i) {
        short8 s;
#pragma unroll
        for (int j = 0; j < 4; ++j) {
          s[j] = (short)(w[2 * i][j] & 0xffffu);
          s[4 + j] = (short)(w[2 * i + 1][j] & 0xffffu);
        }
        av[i] = s;
      }
      return;
    }
    if (spins > 4) __builtin_amdgcn_s_sleep(1);
  }
}

// ---------------------------------------------------------------------------
__global__ void pack_bf(const float* __restrict__ in, unsigned short* __restrict__ out, int n) {
  int i = blockIdx.x * 256 + threadIdx.x;
  if (i < n) out[i] = f2bf(in[i]);
}

__global__ void packT(const float* __restrict__ src, int srcStride,
                      unsigned short* __restrict__ dst, int dldk, int koff) {
  __shared__ float tile[32][33];
  int tx = threadIdx.x, ty = threadIdx.y;
  int e0 = blockIdx.x * 32, k0 = blockIdx.y * 32;
#pragma unroll
  for (int i = 0; i < 4; ++i)
    tile[ty + 8 * i][tx] = src[(size_t)(k0 + ty + 8 * i) * srcStride + e0 + tx];
  __syncthreads();
#pragma unroll
  for (int i = 0; i < 4; ++i)
    dst[(size_t)(e0 + ty + 8 * i) * dldk + koff + k0 + tx] = f2bf(tile[tx][ty + 8 * i]);
}

__global__ void sentinel(float* out, float v) { out[0] = v; }

// ---------------------------------------------------------------------------
// Big MFMA GEMM (unchanged, verified)
// ---------------------------------------------------------------------------
template <int EPI>
__global__ __launch_bounds__(256) void gemm_bt(
    const unsigned short* __restrict__ A0, const unsigned short* __restrict__ A1,
    const unsigned short* __restrict__ BT,
    int M, int Nn, int K, int KA0,
    const float* __restrict__ bias,
    unsigned short* __restrict__ out_bf,
    const float* __restrict__ xf,
    float* __restrict__ ud,
    unsigned short* __restrict__ rdx,
    float* __restrict__ outf) {
  __shared__ unsigned short At[128 * 32];
  __shared__ unsigned short Bt[128 * 32];
  const int tid = threadIdx.x;
  const int lane = tid & 63, wave = tid >> 6;
  const int wm = wave >> 1, wn = wave & 1;
  const int m0 = blockIdx.y * 128, n0 = blockIdx.x * 128;
  const int lr = lane & 15, lk = (lane >> 4) * 8;
  floatx4 acc[4][4] = {};

  for (int k0 = 0; k0 < K; k0 += 32) {
    const unsigned short* As;
    int kk;
    if (k0 < KA0) { As = A0 + (size_t)m0 * KA0 + k0; kk = KA0; }
    else          { As = A1 + (size_t)m0 * (K - KA0) + (k0 - KA0); kk = K - KA0; }
#pragma unroll
    for (int j = 0; j < 2; ++j) {
      int chunk = j * 256 + tid;
      int row = chunk >> 2, kc = chunk & 3;
      gload16(As + (size_t)row * kk + kc * 8, (const char*)At + chunk * 16);
    }
    const unsigned short* Bs = BT + (size_t)n0 * K + k0;
#pragma unroll
    for (int j = 0; j < 2; ++j) {
      int chunk = j * 256 + tid;
      int row = chunk >> 2, kc = chunk & 3;
      gload16(Bs + (size_t)row * K + kc * 8, (const char*)Bt + chunk * 16);
    }
    __syncthreads();
    short8 a[4], b[4];
#pragma unroll
    for (int i = 0; i < 4; ++i) a[i] = *(const short8*)(At + (wm * 64 + i * 16 + lr) * 32 + lk);
#pragma unroll
    for (int i = 0; i < 4; ++i) b[i] = *(const short8*)(Bt + (wn * 64 + i * 16 + lr) * 32 + lk);
#pragma unroll
    for (int i = 0; i < 4; ++i)
#pragma unroll
      for (int j = 0; j < 4; ++j)
        acc[i][j] = MFMA16(a[i], b[j], acc[i][j], 0, 0, 0);
    __syncthreads();
  }

#pragma unroll
  for (int i = 0; i < 4; ++i) {
#pragma unroll
    for (int j = 0; j < 4; ++j) {
      int col = n0 + wn * 64 + j * 16 + lr;
#pragma unroll
      for (int r = 0; r < 4; ++r) {
        int row = m0 + wm * 64 + i * 16 + (lane >> 4) * 4 + r;
        float v = acc[i][j][r];
        if constexpr (EPI == 0) {
          out_bf[(size_t)row * Nn + col] = f2bf(v + bias[col]);
        } else if constexpr (EPI == 1) {
          float s = sigm(v + bias[col]);
          if (col < 1024) {
            ud[(size_t)row * 1024 + col] = s;
          } else {
            size_t ix = (size_t)row * 1024 + (col - 1024);
            rdx[ix] = f2bf(s * xf[ix]);
          }
        } else {
          float hc = tanh_fast(v + bias[col]);
          size_t ix = (size_t)row * 1024 + col;
          float xv = xf[ix];
          outf[ix] = xv + ud[ix] * (hc - xv);
        }
      }
    }
  }
}

// ---------------------------------------------------------------------------
// Persistent scan (r7): tagged-dataflow exchange — NO flags, NO drains, NO
// barriers between blocks. State words are u32 = (tag<<16)|bf16. 128 blocks =
// 2 groups x 64 (proven co-resident). Block b owns cols [b*16,b*16+16); each
// thread owns one (row,col). Weights (Wu,Wr,Wc) LDS-resident, XOR-swizzled.
// Step: poll h(tag t+1) -> r-MFMA -> combine -> store rh(tag t+1) early ->
// u-MFMA -> combine (hides rh flight) -> poll rh -> hc-MFMA -> combine ->
// h update -> store h(tag t+2).
// ---------------------------------------------------------------------------
__global__ __launch_bounds__(256, 1) void scan_pk(
    const unsigned short* __restrict__ wgT,   // [2048][1024] u-cols 0-1023, r-cols 1024-2047
    const unsigned short* __restrict__ wcT,   // [1024][1024]
    const unsigned short* __restrict__ gates, // [32*512][3072]
    const float* __restrict__ ph,             // [32][1024]
    unsigned int* __restrict__ hb32,          // [32][1024] tagged h words
    unsigned int* __restrict__ rh32,          // [32][1024] tagged r*h words
    unsigned short* __restrict__ htb,         // [32*512][1024]
    float* __restrict__ lastht)               // [32][1024]
{
  __shared__ unsigned short Wu[16 * 1024];
  __shared__ unsigned short Wr[16 * 1024];
  __shared__ unsigned short Wc[16 * 1024];
  __shared__ float Part[8][16][17];           // [0..3]=r then hc, [4..7]=u

  const int tid = threadIdx.x;
  const int lane = tid & 63, wave = tid >> 6;
  const int lr = lane & 15, lq = lane >> 4;
  const int g = blockIdx.x >> 6, b = blockIdx.x & 63;
  const int row0 = g * 16, col0 = b * 16;
  const int myrow = tid >> 4, myc = tid & 15;

  // ---- stage weight slices into LDS (source pre-swizzled: chunk ^= col&7) ----
#pragma unroll
  for (int i = 0; i < 8; ++i) {
    int p = i * 256 + tid;                 // 2048 chunks of 16B per array
    int wr = p >> 7, kcp = p & 127;
    int kc = kcp ^ (wr & 7);
    gload16(wgT + (size_t)(col0 + wr) * 1024 + kc * 8,        (const char*)Wu + p * 16);
    gload16(wgT + (size_t)(1024 + col0 + wr) * 1024 + kc * 8, (const char*)Wr + p * 16);
    gload16(wcT + (size_t)(col0 + wr) * 1024 + kc * 8,        (const char*)Wc + p * 16);
  }

  // ---- init: per-thread h element, tag 1 ----
  float Hl = ph[(size_t)(row0 + myrow) * 1024 + col0 + myc];
  st_tag(&hb32[(size_t)(row0 + myrow) * 1024 + col0 + myc], (1u << 16) | f2bf(Hl));
  __syncthreads();                         // weights resident (vmcnt drained)

  const unsigned int* hqbase = hb32 + (size_t)(row0 + lr) * 1024 + wave * 256 + lq * 8;
  const unsigned int* rqbase = rh32 + (size_t)(row0 + lr) * 1024 + wave * 256 + lq * 8;

  for (int t = 0; t < T_STEPS; ++t) {
    // gate loads (plain, cached — caches never invalidated in this design)
    size_t gbase = ((size_t)(row0 + myrow) * T_STEPS + t) * 3072 + col0 + myc;
    unsigned short gU = gates[gbase];
    unsigned short gR = gates[gbase + 1024];
    unsigned short gC = gates[gbase + 2048];

    // ---- poll h(t): wave-local K-quarter, tag >= t+1 ----
    short8 av[8];
    poll_frags(hqbase, (unsigned)(t + 1), av);

    // ---- r-chain MFMA ----
    {
      floatx4 aR = {};
#pragma unroll
      for (int kc = 0; kc < 8; ++kc) {
        int ch = (wave * 32 + kc * 4 + lq) ^ (lr & 7);
        short8 bR = *(const short8*)(Wr + lr * 1024 + ch * 8);
        aR = MFMA16(av[kc], bR, aR, 0, 0, 0);
      }
#pragma unroll
      for (int r = 0; r < 4; ++r) Part[wave][lq * 4 + r][lr] = aR[r];
    }
    __syncthreads();                       // (A)
    {
      float rpre = Part[0][myrow][myc] + Part[1][myrow][myc] +
                   Part[2][myrow][myc] + Part[3][myrow][myc];
      float rv = sigm(rpre + bf2f(gR));
      st_tag(&rh32[(size_t)(row0 + myrow) * 1024 + col0 + myc],
             ((unsigned)(t + 1) << 16) | f2bf(rv * Hl));   // out early, flight hides under u
    }

    // ---- u-chain MFMA (independent; hides rh broadcast flight) ----
    {
      floatx4 aU = {};
#pragma unroll
      for (int kc = 0; kc < 8; ++kc) {
        int ch = (wave * 32 + kc * 4 + lq) ^ (lr & 7);
        short8 bU = *(const short8*)(Wu + lr * 1024 + ch * 8);
        aU = MFMA16(av[kc], bU, aU, 0, 0, 0);
      }
#pragma unroll
      for (int r = 0; r < 4; ++r) Part[4 + wave][lq * 4 + r][lr] = aU[r];
    }
    __syncthreads();                       // (B)
    float uv;
    {
      float upre = Part[4][myrow][myc] + Part[5][myrow][myc] +
                   Part[6][myrow][myc] + Part[7][myrow][myc];
      uv = sigm(upre + bf2f(gU));
    }

    // ---- poll rh(t), then hc-chain ----
    short8 av2[8];
    poll_frags(rqbase, (unsigned)(t + 1), av2);
    {
      floatx4 c0 = {}, c1 = {};
#pragma unroll
      for (int kc = 0; kc < 8; kc += 2) {
        int ch0 = (wave * 32 + kc * 4 + lq) ^ (lr & 7);
        int ch1 = (wave * 32 + (kc + 1) * 4 + lq) ^ (lr & 7);
        short8 b0 = *(const short8*)(Wc + lr * 1024 + ch0 * 8);
        short8 b1 = *(const short8*)(Wc + lr * 1024 + ch1 * 8);
        c0 = MFMA16(av2[kc], b0, c0, 0, 0, 0);
        c1 = MFMA16(av2[kc + 1], b1, c1, 0, 0, 0);
      }
#pragma unroll
      for (int r = 0; r < 4; ++r) Part[wave][lq * 4 + r][lr] = c0[r] + c1[r];
    }
    __syncthreads();                       // (C)
    {
      float cpre = Part[0][myrow][myc] + Part[1][myrow][myc] +
                   Part[2][myrow][myc] + Part[3][myrow][myc];
      float hc = tanh_fast(cpre + bf2f(gC));
      float hn = Hl + uv * (hc - Hl);
      Hl = hn;
      unsigned short hv = f2bf(hn);
      st_tag(&hb32[(size_t)(row0 + myrow) * 1024 + col0 + myc],
             ((unsigned)(t + 2) << 16) | hv);
      htb[((size_t)(row0 + myrow) * T_STEPS + t) * 1024 + col0 + myc] = hv;
      if (t == T_STEPS - 1) lastht[(size_t)(row0 + myrow) * 1024 + col0 + myc] = hn;
    }
    __syncthreads();                       // (D) Part reuse guard for next step
  }
}

// ---------------------------------------------------------------------------
extern "C" void kernel_launch(void* const* d_in, const int* in_sizes, int n_in,
                              void* d_out, int out_size, void* d_ws, size_t ws_size,
                              hipStream_t stream) {
  const float* x    = (const float*)d_in[0];   // (32,512,1024)
  const float* ph   = (const float*)d_in[1];   // (32,1024)
  const float* wgt  = (const float*)d_in[2];   // (2048,6144)
  const float* bias = (const float*)d_in[3];   // (6144,)
  float* out = (float*)d_out;                  // h (16777216) + last_ht (32768)

  const size_t SZ_STATE = (size_t)32 * 1024 * 4 * 2;  // hb32 + rh32 (tagged u32)
  const size_t SZ_XBF   = (size_t)16384 * 1024 * 2;
  const size_t SZ_GATES = (size_t)16384 * 3072 * 2;   // rdx aliases here after scan
  const size_t SZ_HTB   = (size_t)16384 * 1024 * 2;
  const size_t SZ_W     = ((size_t)3072 * 1024 + (size_t)2048 * 2048 +
                           (size_t)1024 * 2048 + (size_t)2048 * 1024 +
                           (size_t)1024 * 1024) * 2;
  const size_t REQUIRED = SZ_STATE + SZ_XBF + SZ_GATES + SZ_HTB + SZ_W;

  if (ws_size < REQUIRED) {
    sentinel<<<1, 1, 0, stream>>>(out, (float)ws_size);
    return;
  }

  char* p = (char*)d_ws;
  unsigned int* hb32    = (unsigned int*)p;   p += (size_t)32 * 1024 * 4;
  unsigned int* rh32    = (unsigned int*)p;   p += (size_t)32 * 1024 * 4;
  unsigned short* xbf   = (unsigned short*)p; p += SZ_XBF;
  unsigned short* gates = (unsigned short*)p;
  unsigned short* rdx   = (unsigned short*)p; p += SZ_GATES;
  unsigned short* htb   = (unsigned short*)p; p += SZ_HTB;
  unsigned short* wxtT  = (unsigned short*)p; p += (size_t)3072 * 1024 * 2;
  unsigned short* w1T   = (unsigned short*)p; p += (size_t)2048 * 2048 * 2;
  unsigned short* w2T   = (unsigned short*)p; p += (size_t)1024 * 2048 * 2;
  unsigned short* wgT   = (unsigned short*)p; p += (size_t)2048 * 1024 * 2;
  unsigned short* wcT   = (unsigned short*)p; p += (size_t)1024 * 1024 * 2;
  float* udf = out;  // ud aliases d_out's h region; see gemm epilogues

  // tags must start at 0 each launch (graph replays reuse the buffers)
  hipMemsetAsync(hb32, 0, SZ_STATE, stream);

  dim3 tb(32, 8);
  pack_bf<<<65536, 256, 0, stream>>>(x, xbf, 16384 * 1024);
  packT<<<dim3(96, 32), tb, 0, stream>>>(wgt, 6144, wxtT, 1024, 0);
  packT<<<dim3(64, 64), tb, 0, stream>>>(wgt + 3072, 6144, w1T, 2048, 0);
  packT<<<dim3(32, 32), tb, 0, stream>>>(wgt + (size_t)1024 * 6144 + 5120, 6144, w2T, 2048, 0);
  packT<<<dim3(32, 32), tb, 0, stream>>>(wgt + 5120, 6144, w2T, 2048, 1024);
  packT<<<dim3(64, 32), tb, 0, stream>>>(wgt + (size_t)1024 * 6144, 6144, wgT, 1024, 0);
  packT<<<dim3(32, 32), tb, 0, stream>>>(wgt + (size_t)1024 * 6144 + 2048, 6144, wcT, 1024, 0);

  gemm_bt<0><<<dim3(24, 128), 256, 0, stream>>>(xbf, xbf, wxtT, 16384, 3072, 1024, 1024,
                                                bias, gates, nullptr, nullptr, nullptr, nullptr);

  // persistent recurrence: 128 blocks (proven co-resident), tagged dataflow
  scan_pk<<<128, 256, 0, stream>>>(wgT, wcT, gates, ph, hb32, rh32, htb,
                                   out + (size_t)16384 * 1024);

  gemm_bt<1><<<dim3(16, 128), 256, 0, stream>>>(xbf, htb, w1T, 16384, 2048, 2048, 1024,
                                                bias + 3072, nullptr, x, udf, rdx, nullptr);
  gemm_bt<2><<<dim3(8, 128), 256, 0, stream>>>(htb, rdx, w2T, 16384, 1024, 2048, 1024,
                                               bias + 5120, nullptr, x, udf, nullptr, out);
}

// Round 8
// 3347.660 us; speedup vs baseline: 1.6316x; 1.5054x over previous
//
#include <hip/hip_runtime.h>
#include <stdint.h>

#define T_STEPS 512

typedef short short8 __attribute__((ext_vector_type(8)));
typedef float floatx4 __attribute__((ext_vector_type(4)));
typedef unsigned int u32x4 __attribute__((ext_vector_type(4)));
typedef unsigned int u32x2 __attribute__((ext_vector_type(2)));

#define MFMA16 __builtin_amdgcn_mfma_f32_16x16x32_bf16

__device__ __forceinline__ unsigned short f2bf(float f) {
  unsigned int u = __builtin_bit_cast(unsigned int, f);
  u = u + 0x7fff + ((u >> 16) & 1);
  return (unsigned short)(u >> 16);
}
__device__ __forceinline__ float bf2f(unsigned short s) {
  unsigned int u = ((unsigned int)s) << 16;
  return __builtin_bit_cast(float, u);
}
__device__ __forceinline__ float sigm(float x) { return 1.f / (1.f + __expf(-x)); }
__device__ __forceinline__ float tanh_fast(float x) {
  float e2 = __expf(2.f * x);
  return 1.f - 2.f / (e2 + 1.f);
}

__device__ __forceinline__ void gload16(const void* g, const void* l) {
  __builtin_amdgcn_global_load_lds((const __attribute__((address_space(1))) unsigned int*)g,
                                   (__attribute__((address_space(3))) unsigned int*)l,
                                   16, 0, 0);
}

// Fire-and-forget tagged-word store (LLC-coherent). u32 = (tag<<16)|bf16.
__device__ __forceinline__ void st_tag(unsigned int* p, unsigned int word) {
  asm volatile("global_store_dword %0, %1, off sc0 sc1" :: "v"(p), "v"(word) : "memory");
}

// ---------------------------------------------------------------------------
// Bulk tagged stage: read the group's full [16][1024] tagged state with
// instruction-contiguous sc0sc1 loads (1KB/instr per wave), retry until all
// tags >= target, strip tags, pack bf16 pairs, write swizzled LDS Stg.
// Ends with __syncthreads (Stg consistent). Bounded spin - no hang.
// ---------------------------------------------------------------------------
__device__ __forceinline__ void stage_state(const unsigned int* __restrict__ gsrc,
                                            unsigned int target,
                                            unsigned short* Stg, int tid) {
  const int lane = tid & 63, wave = tid >> 6;
  const unsigned int* src = gsrc + wave * 4096 + lane * 4;
  u32x4 w[16];
  int spins = 0;
  for (;;) {
#pragma unroll
    for (int j = 0; j < 16; ++j)
      asm volatile("global_load_dwordx4 %0, %1, off sc0 sc1"
                   : "=v"(w[j]) : "v"(src + j * 256));
    asm volatile("s_waitcnt vmcnt(0)" ::: "memory");
    __builtin_amdgcn_sched_barrier(0);
    bool ok = true;
#pragma unroll
    for (int j = 0; j < 16; ++j)
#pragma unroll
      for (int q = 0; q < 4; ++q) ok &= ((w[j][q] >> 16) >= target);
    if (__all((int)ok) || ++spins > (1 << 15)) break;   // valve: no hang
    if (spins > 4) __builtin_amdgcn_s_sleep(1);
  }
  // pack (strip tags) and write swizzled LDS: chunk16 c at row r lands at c^(r&7)
  const int half = lane & 1;
  const int chb = lane >> 1;
#pragma unroll
  for (int j = 0; j < 16; ++j) {
    int row = wave * 4 + (j >> 2);
    int c16 = (j & 3) * 32 + chb;
    u32x2 v;
    v[0] = (w[j][0] & 0xffffu) | (w[j][1] << 16);
    v[1] = (w[j][2] & 0xffffu) | (w[j][3] << 16);
    *(u32x2*)((char*)Stg + row * 2048 + ((c16 ^ (row & 7)) * 16) + half * 8) = v;
  }
  __syncthreads();
}

// ---------------------------------------------------------------------------
__global__ void pack_bf(const float* __restrict__ in, unsigned short* __restrict__ out, int n) {
  int i = blockIdx.x * 256 + threadIdx.x;
  if (i < n) out[i] = f2bf(in[i]);
}

__global__ void packT(const float* __restrict__ src, int srcStride,
                      unsigned short* __restrict__ dst, int dldk, int koff) {
  __shared__ float tile[32][33];
  int tx = threadIdx.x, ty = threadIdx.y;
  int e0 = blockIdx.x * 32, k0 = blockIdx.y * 32;
#pragma unroll
  for (int i = 0; i < 4; ++i)
    tile[ty + 8 * i][tx] = src[(size_t)(k0 + ty + 8 * i) * srcStride + e0 + tx];
  __syncthreads();
#pragma unroll
  for (int i = 0; i < 4; ++i)
    dst[(size_t)(e0 + ty + 8 * i) * dldk + koff + k0 + tx] = f2bf(tile[tx][ty + 8 * i]);
}

__global__ void sentinel(float* out, float v) { out[0] = v; }

// ---------------------------------------------------------------------------
// Big MFMA GEMM (unchanged, verified)
// ---------------------------------------------------------------------------
template <int EPI>
__global__ __launch_bounds__(256) void gemm_bt(
    const unsigned short* __restrict__ A0, const unsigned short* __restrict__ A1,
    const unsigned short* __restrict__ BT,
    int M, int Nn, int K, int KA0,
    const float* __restrict__ bias,
    unsigned short* __restrict__ out_bf,
    const float* __restrict__ xf,
    float* __restrict__ ud,
    unsigned short* __restrict__ rdx,
    float* __restrict__ outf) {
  __shared__ unsigned short At[128 * 32];
  __shared__ unsigned short Bt[128 * 32];
  const int tid = threadIdx.x;
  const int lane = tid & 63, wave = tid >> 6;
  const int wm = wave >> 1, wn = wave & 1;
  const int m0 = blockIdx.y * 128, n0 = blockIdx.x * 128;
  const int lr = lane & 15, lk = (lane >> 4) * 8;
  floatx4 acc[4][4] = {};

  for (int k0 = 0; k0 < K; k0 += 32) {
    const unsigned short* As;
    int kk;
    if (k0 < KA0) { As = A0 + (size_t)m0 * KA0 + k0; kk = KA0; }
    else          { As = A1 + (size_t)m0 * (K - KA0) + (k0 - KA0); kk = K - KA0; }
#pragma unroll
    for (int j = 0; j < 2; ++j) {
      int chunk = j * 256 + tid;
      int row = chunk >> 2, kc = chunk & 3;
      gload16(As + (size_t)row * kk + kc * 8, (const char*)At + chunk * 16);
    }
    const unsigned short* Bs = BT + (size_t)n0 * K + k0;
#pragma unroll
    for (int j = 0; j < 2; ++j) {
      int chunk = j * 256 + tid;
      int row = chunk >> 2, kc = chunk & 3;
      gload16(Bs + (size_t)row * K + kc * 8, (const char*)Bt + chunk * 16);
    }
    __syncthreads();
    short8 a[4], b[4];
#pragma unroll
    for (int i = 0; i < 4; ++i) a[i] = *(const short8*)(At + (wm * 64 + i * 16 + lr) * 32 + lk);
#pragma unroll
    for (int i = 0; i < 4; ++i) b[i] = *(const short8*)(Bt + (wn * 64 + i * 16 + lr) * 32 + lk);
#pragma unroll
    for (int i = 0; i < 4; ++i)
#pragma unroll
      for (int j = 0; j < 4; ++j)
        acc[i][j] = MFMA16(a[i], b[j], acc[i][j], 0, 0, 0);
    __syncthreads();
  }

#pragma unroll
  for (int i = 0; i < 4; ++i) {
#pragma unroll
    for (int j = 0; j < 4; ++j) {
      int col = n0 + wn * 64 + j * 16 + lr;
#pragma unroll
      for (int r = 0; r < 4; ++r) {
        int row = m0 + wm * 64 + i * 16 + (lane >> 4) * 4 + r;
        float v = acc[i][j][r];
        if constexpr (EPI == 0) {
          out_bf[(size_t)row * Nn + col] = f2bf(v + bias[col]);
        } else if constexpr (EPI == 1) {
          float s = sigm(v + bias[col]);
          if (col < 1024) {
            ud[(size_t)row * 1024 + col] = s;
          } else {
            size_t ix = (size_t)row * 1024 + (col - 1024);
            rdx[ix] = f2bf(s * xf[ix]);
          }
        } else {
          float hc = tanh_fast(v + bias[col]);
          size_t ix = (size_t)row * 1024 + col;
          float xv = xf[ix];
          outf[ix] = xv + ud[ix] * (hc - xv);
        }
      }
    }
  }
}

// ---------------------------------------------------------------------------
// Persistent scan (r8): tagged dataflow (r7 protocol) + bulk contiguous
// staging into swizzled LDS (r4 access pattern). 128 blocks = 2 groups x 64.
// Block b owns cols [b*16,b*16+16); thread owns one (row,col). Weights
// Wu/Wr/Wc LDS-resident. Per step: stage-poll h -> r-MFMA -> combine ->
// store rh(tag t+1) -> u-MFMA -> combine (hides rh flight) -> stage-poll rh
// -> hc-MFMA -> combine -> h update -> store h(tag t+2).
// ---------------------------------------------------------------------------
__global__ __launch_bounds__(256, 1) void scan_pk(
    const unsigned short* __restrict__ wgT,   // [2048][1024] u-cols 0-1023, r-cols 1024-2047
    const unsigned short* __restrict__ wcT,   // [1024][1024]
    const unsigned short* __restrict__ gates, // [32*512][3072]
    const float* __restrict__ ph,             // [32][1024]
    unsigned int* __restrict__ hb32,          // [32][1024] tagged h words
    unsigned int* __restrict__ rh32,          // [32][1024] tagged r*h words
    unsigned short* __restrict__ htb,         // [32*512][1024]
    float* __restrict__ lastht)               // [32][1024]
{
  __shared__ unsigned short Wu[16 * 1024];
  __shared__ unsigned short Wr[16 * 1024];
  __shared__ unsigned short Wc[16 * 1024];
  __shared__ unsigned short Stg[16 * 1024];   // packed bf16 state (swizzled)
  __shared__ float Part[8][16][17];           // [0..3]=r then hc, [4..7]=u

  const int tid = threadIdx.x;
  const int lane = tid & 63, wave = tid >> 6;
  const int lr = lane & 15, lq = lane >> 4;
  const int g = blockIdx.x >> 6, b = blockIdx.x & 63;
  const int row0 = g * 16, col0 = b * 16;
  const int myrow = tid >> 4, myc = tid & 15;

  // ---- stage weight slices into LDS (source pre-swizzled: chunk ^= row&7) ----
#pragma unroll
  for (int i = 0; i < 8; ++i) {
    int p = i * 256 + tid;                 // 2048 chunks of 16B per array
    int wr = p >> 7, kcp = p & 127;
    int kc = kcp ^ (wr & 7);
    gload16(wgT + (size_t)(col0 + wr) * 1024 + kc * 8,        (const char*)Wu + p * 16);
    gload16(wgT + (size_t)(1024 + col0 + wr) * 1024 + kc * 8, (const char*)Wr + p * 16);
    gload16(wcT + (size_t)(col0 + wr) * 1024 + kc * 8,        (const char*)Wc + p * 16);
  }

  // ---- init: per-thread h element, tag 1 ----
  float Hl = ph[(size_t)(row0 + myrow) * 1024 + col0 + myc];
  st_tag(&hb32[(size_t)(row0 + myrow) * 1024 + col0 + myc], (1u << 16) | f2bf(Hl));
  __syncthreads();                         // weights resident (vmcnt drained)

  const unsigned int* hb32g = hb32 + (size_t)row0 * 1024;
  const unsigned int* rh32g = rh32 + (size_t)row0 * 1024;

  for (int t = 0; t < T_STEPS; ++t) {
    // gate loads (plain cached; issued before the poll so latency overlaps)
    size_t gbase = ((size_t)(row0 + myrow) * T_STEPS + t) * 3072 + col0 + myc;
    unsigned short gU = gates[gbase];
    unsigned short gR = gates[gbase + 1024];
    unsigned short gC = gates[gbase + 2048];

    // ---- stage-poll h(t) into Stg ----
    stage_state(hb32g, (unsigned)(t + 1), Stg, tid);

    // ---- r-MFMA: 4-wave K-split, B from Wr ----
    {
      floatx4 aR = {};
#pragma unroll
      for (int ks = 0; ks < 8; ++ks) {
        int sw = ((wave * 8 + ks) * 4 + lq) ^ (lr & 7);
        short8 a = *(const short8*)(Stg + lr * 1024 + sw * 8);
        short8 bR = *(const short8*)(Wr + lr * 1024 + sw * 8);
        aR = MFMA16(a, bR, aR, 0, 0, 0);
      }
#pragma unroll
      for (int r = 0; r < 4; ++r) Part[wave][lq * 4 + r][lr] = aR[r];
    }
    __syncthreads();
    {
      float rpre = Part[0][myrow][myc] + Part[1][myrow][myc] +
                   Part[2][myrow][myc] + Part[3][myrow][myc];
      float rv = sigm(rpre + bf2f(gR));
      st_tag(&rh32[(size_t)(row0 + myrow) * 1024 + col0 + myc],
             ((unsigned)(t + 1) << 16) | f2bf(rv * Hl));   // out early; flight hides under u
    }

    // ---- u-MFMA (independent; Part[4..7] disjoint from r-combine reads) ----
    {
      floatx4 aU = {};
#pragma unroll
      for (int ks = 0; ks < 8; ++ks) {
        int sw = ((wave * 8 + ks) * 4 + lq) ^ (lr & 7);
        short8 a = *(const short8*)(Stg + lr * 1024 + sw * 8);
        short8 bU = *(const short8*)(Wu + lr * 1024 + sw * 8);
        aU = MFMA16(a, bU, aU, 0, 0, 0);
      }
#pragma unroll
      for (int r = 0; r < 4; ++r) Part[4 + wave][lq * 4 + r][lr] = aU[r];
    }
    __syncthreads();
    float uv;
    {
      float upre = Part[4][myrow][myc] + Part[5][myrow][myc] +
                   Part[6][myrow][myc] + Part[7][myrow][myc];
      uv = sigm(upre + bf2f(gU));
    }

    // ---- stage-poll rh(t) into Stg (overwrites h; u-MFMA done per syncs) ----
    stage_state(rh32g, (unsigned)(t + 1), Stg, tid);

    // ---- hc-MFMA ----
    {
      floatx4 c0 = {}, c1 = {};
#pragma unroll
      for (int ks = 0; ks < 8; ks += 2) {
        int sw0 = ((wave * 8 + ks) * 4 + lq) ^ (lr & 7);
        int sw1 = ((wave * 8 + ks + 1) * 4 + lq) ^ (lr & 7);
        short8 a0 = *(const short8*)(Stg + lr * 1024 + sw0 * 8);
        short8 a1 = *(const short8*)(Stg + lr * 1024 + sw1 * 8);
        short8 b0 = *(const short8*)(Wc + lr * 1024 + sw0 * 8);
        short8 b1 = *(const short8*)(Wc + lr * 1024 + sw1 * 8);
        c0 = MFMA16(a0, b0, c0, 0, 0, 0);
        c1 = MFMA16(a1, b1, c1, 0, 0, 0);
      }
#pragma unroll
      for (int r = 0; r < 4; ++r) Part[wave][lq * 4 + r][lr] = c0[r] + c1[r];
    }
    __syncthreads();
    {
      float cpre = Part[0][myrow][myc] + Part[1][myrow][myc] +
                   Part[2][myrow][myc] + Part[3][myrow][myc];
      float hc = tanh_fast(cpre + bf2f(gC));
      float hn = Hl + uv * (hc - Hl);
      Hl = hn;
      unsigned short hv = f2bf(hn);
      st_tag(&hb32[(size_t)(row0 + myrow) * 1024 + col0 + myc],
             ((unsigned)(t + 2) << 16) | hv);
      htb[((size_t)(row0 + myrow) * T_STEPS + t) * 1024 + col0 + myc] = hv;
      if (t == T_STEPS - 1) lastht[(size_t)(row0 + myrow) * 1024 + col0 + myc] = hn;
    }
  }
}

// ---------------------------------------------------------------------------
extern "C" void kernel_launch(void* const* d_in, const int* in_sizes, int n_in,
                              void* d_out, int out_size, void* d_ws, size_t ws_size,
                              hipStream_t stream) {
  const float* x    = (const float*)d_in[0];   // (32,512,1024)
  const float* ph   = (const float*)d_in[1];   // (32,1024)
  const float* wgt  = (const float*)d_in[2];   // (2048,6144)
  const float* bias = (const float*)d_in[3];   // (6144,)
  float* out = (float*)d_out;                  // h (16777216) + last_ht (32768)

  const size_t SZ_STATE = (size_t)32 * 1024 * 4 * 2;  // hb32 + rh32 (tagged u32)
  const size_t SZ_XBF   = (size_t)16384 * 1024 * 2;
  const size_t SZ_GATES = (size_t)16384 * 3072 * 2;   // rdx aliases here after scan
  const size_t SZ_HTB   = (size_t)16384 * 1024 * 2;
  const size_t SZ_W     = ((size_t)3072 * 1024 + (size_t)2048 * 2048 +
                           (size_t)1024 * 2048 + (size_t)2048 * 1024 +
                           (size_t)1024 * 1024) * 2;
  const size_t REQUIRED = SZ_STATE + SZ_XBF + SZ_GATES + SZ_HTB + SZ_W;

  if (ws_size < REQUIRED) {
    sentinel<<<1, 1, 0, stream>>>(out, (float)ws_size);
    return;
  }

  char* p = (char*)d_ws;
  unsigned int* hb32    = (unsigned int*)p;   p += (size_t)32 * 1024 * 4;
  unsigned int* rh32    = (unsigned int*)p;   p += (size_t)32 * 1024 * 4;
  unsigned short* xbf   = (unsigned short*)p; p += SZ_XBF;
  unsigned short* gates = (unsigned short*)p;
  unsigned short* rdx   = (unsigned short*)p; p += SZ_GATES;
  unsigned short* htb   = (unsigned short*)p; p += SZ_HTB;
  unsigned short* wxtT  = (unsigned short*)p; p += (size_t)3072 * 1024 * 2;
  unsigned short* w1T   = (unsigned short*)p; p += (size_t)2048 * 2048 * 2;
  unsigned short* w2T   = (unsigned short*)p; p += (size_t)1024 * 2048 * 2;
  unsigned short* wgT   = (unsigned short*)p; p += (size_t)2048 * 1024 * 2;
  unsigned short* wcT   = (unsigned short*)p; p += (size_t)1024 * 1024 * 2;
  float* udf = out;  // ud aliases d_out's h region; see gemm epilogues

  // tags must start at 0 each launch (graph replays reuse the buffers)
  hipMemsetAsync(hb32, 0, SZ_STATE, stream);

  dim3 tb(32, 8);
  pack_bf<<<65536, 256, 0, stream>>>(x, xbf, 16384 * 1024);
  packT<<<dim3(96, 32), tb, 0, stream>>>(wgt, 6144, wxtT, 1024, 0);
  packT<<<dim3(64, 64), tb, 0, stream>>>(wgt + 3072, 6144, w1T, 2048, 0);
  packT<<<dim3(32, 32), tb, 0, stream>>>(wgt + (size_t)1024 * 6144 + 5120, 6144, w2T, 2048, 0);
  packT<<<dim3(32, 32), tb, 0, stream>>>(wgt + 5120, 6144, w2T, 2048, 1024);
  packT<<<dim3(64, 32), tb, 0, stream>>>(wgt + (size_t)1024 * 6144, 6144, wgT, 1024, 0);
  packT<<<dim3(32, 32), tb, 0, stream>>>(wgt + (size_t)1024 * 6144 + 2048, 6144, wcT, 1024, 0);

  gemm_bt<0><<<dim3(24, 128), 256, 0, stream>>>(xbf, xbf, wxtT, 16384, 3072, 1024, 1024,
                                                bias, gates, nullptr, nullptr, nullptr, nullptr);

  // persistent recurrence: 128 blocks (proven co-resident), tagged dataflow
  scan_pk<<<128, 256, 0, stream>>>(wgT, wcT, gates, ph, hb32, rh32, htb,
                                   out + (size_t)16384 * 1024);

  gemm_bt<1><<<dim3(16, 128), 256, 0, stream>>>(xbf, htb, w1T, 16384, 2048, 2048, 1024,
                                                bias + 3072, nullptr, x, udf, rdx, nullptr);
  gemm_bt<2><<<dim3(8, 128), 256, 0, stream>>>(htb, rdx, w2T, 16384, 1024, 2048, 1024,
                                               bias + 5120, nullptr, x, udf, nullptr, out);
}